// Round 1
// baseline (1533.372 us; speedup 1.0000x reference)
//
#include <hip/hip_runtime.h>

#define D_MODEL 512
#define NH 8
#define HD_ 64
#define NUM_I 3
#define B_ 4
#define NSEQ 8192
#define SSEQ 4096

// workspace layout (float elements)
static constexpr size_t Q_OFF    = 0;                        // 4*8192*512  = 16777216
static constexpr size_t K_OFF    = Q_OFF  + (size_t)B_*NSEQ*D_MODEL;   // 8388608
static constexpr size_t V_OFF    = K_OFF  + (size_t)B_*SSEQ*D_MODEL;   // 8388608
static constexpr size_t KV_OFF   = V_OFF  + (size_t)B_*SSEQ*D_MODEL;   // 393216
static constexpr size_t KS_OFF   = KV_OFF + (size_t)NUM_I*B_*NH*HD_*HD_; // 6144
static constexpr size_t FLAG_OFF = KS_OFF + (size_t)NUM_I*B_*NH*HD_;   // 1 int

// Detect mask storage: int32 (every word 0/1) vs packed numpy bool bytes.
__global__ void mask_mode_kernel(const int* __restrict__ m, int* __restrict__ flag)
{
    __shared__ int any;
    if (threadIdx.x == 0) any = 0;
    __syncthreads();
    const unsigned v = (unsigned)m[threadIdx.x];
    if (v > 1u) atomicOr(&any, 1);
    __syncthreads();
    if (threadIdx.x == 0) *flag = any;
}

// C[m][n] = sum_k A[m][k]*W[n][k] + bias[n]; EPI: 0 none, 1 softmax(per 64-col head), 2 softmax+mask
template<int EPI>
__global__ __launch_bounds__(256)
void proj_kernel(const float* __restrict__ A, const float* __restrict__ W,
                 const float* __restrict__ bias, const int* __restrict__ mask,
                 const int* __restrict__ maskmode, float* __restrict__ C)
{
    __shared__ __align__(16) float As[16][128];
    __shared__ __align__(16) float Bs[16][64];
    const int tid = threadIdx.x;
    const int tx = tid & 15, ty = tid >> 4;
    const int m0 = blockIdx.x * 128;
    const int n0 = blockIdx.y * 64;

    float acc[8][4];
#pragma unroll
    for (int r = 0; r < 8; ++r)
#pragma unroll
        for (int c = 0; c < 4; ++c) acc[r][c] = 0.f;

    const int arow = tid >> 2;           // 0..63
    const int akq  = (tid & 3) << 2;     // 0,4,8,12
    const float* Arow0 = A + (size_t)(m0 + arow) * D_MODEL + akq;
    const float* Arow1 = Arow0 + (size_t)64 * D_MODEL;
    const float* Wrow  = W + (size_t)(n0 + arow) * D_MODEL + akq;

    for (int k0 = 0; k0 < D_MODEL; k0 += 16) {
        const float4 a0 = *(const float4*)(Arow0 + k0);
        const float4 a1 = *(const float4*)(Arow1 + k0);
        const float4 w0 = *(const float4*)(Wrow  + k0);
        __syncthreads();
        As[akq+0][arow]    = a0.x; As[akq+1][arow]    = a0.y;
        As[akq+2][arow]    = a0.z; As[akq+3][arow]    = a0.w;
        As[akq+0][arow+64] = a1.x; As[akq+1][arow+64] = a1.y;
        As[akq+2][arow+64] = a1.z; As[akq+3][arow+64] = a1.w;
        Bs[akq+0][arow] = w0.x; Bs[akq+1][arow] = w0.y;
        Bs[akq+2][arow] = w0.z; Bs[akq+3][arow] = w0.w;
        __syncthreads();
#pragma unroll
        for (int kk = 0; kk < 16; ++kk) {
            const float4 fa0 = *(const float4*)&As[kk][ty*8];
            const float4 fa1 = *(const float4*)&As[kk][ty*8+4];
            const float4 fb  = *(const float4*)&Bs[kk][tx*4];
            const float av[8] = {fa0.x,fa0.y,fa0.z,fa0.w,fa1.x,fa1.y,fa1.z,fa1.w};
            const float bv[4] = {fb.x,fb.y,fb.z,fb.w};
#pragma unroll
            for (int r = 0; r < 8; ++r)
#pragma unroll
                for (int c = 0; c < 4; ++c)
                    acc[r][c] = fmaf(av[r], bv[c], acc[r][c]);
        }
    }

    float bload[4];
#pragma unroll
    for (int c = 0; c < 4; ++c) bload[c] = bias[n0 + tx*4 + c];
#pragma unroll
    for (int r = 0; r < 8; ++r)
#pragma unroll
        for (int c = 0; c < 4; ++c) acc[r][c] += bload[c];

    if (EPI >= 1) {
        // row softmax over the 64 cols of this head tile; row = lanes sharing ty (16 lanes)
#pragma unroll
        for (int r = 0; r < 8; ++r) {
            float mx = fmaxf(fmaxf(acc[r][0], acc[r][1]), fmaxf(acc[r][2], acc[r][3]));
#pragma unroll
            for (int off = 1; off < 16; off <<= 1) mx = fmaxf(mx, __shfl_xor(mx, off));
            float s = 0.f;
#pragma unroll
            for (int c = 0; c < 4; ++c) { acc[r][c] = __expf(acc[r][c] - mx); s += acc[r][c]; }
#pragma unroll
            for (int off = 1; off < 16; off <<= 1) s += __shfl_xor(s, off);
            const float inv = 1.f / s;
#pragma unroll
            for (int c = 0; c < 4; ++c) acc[r][c] *= inv;
        }
    }
    if (EPI == 2) {
        const int bytemode = *maskmode;
#pragma unroll
        for (int r = 0; r < 8; ++r) {
            const int m = m0 + ty*8 + r;
            const bool keep = bytemode ? (((const unsigned char*)mask)[m] != 0)
                                       : (mask[m] != 0);
            if (!keep) {
#pragma unroll
                for (int c = 0; c < 4; ++c) acc[r][c] = 0.f;
            }
        }
    }
#pragma unroll
    for (int r = 0; r < 8; ++r) {
        const float4 o = make_float4(acc[r][0], acc[r][1], acc[r][2], acc[r][3]);
        *(float4*)&C[(size_t)(m0 + ty*8 + r) * D_MODEL + n0 + tx*4] = o;
    }
}

// kv[i,b,h,d,e] += sum_s k[s,d]*v[s,e]; ksum[i,b,h,d] += sum_s k[s,d]  (split over s-chunks)
__global__ __launch_bounds__(256)
void kv_accum_kernel(const float* __restrict__ K, const float* __restrict__ V,
                     float* __restrict__ kv, float* __restrict__ ksum, int i_idx)
{
    const int chunk = blockIdx.x;  // 0..7 (512 s each)
    const int h = blockIdx.y;
    const int b = blockIdx.z;
    __shared__ __align__(16) float ks[32][68];
    __shared__ __align__(16) float vs[32][68];
    const int tid = threadIdx.x;
    const int tx = tid & 15, ty = tid >> 4;
    const int lrow = tid >> 4;
    const int lq = (tid & 15) << 2;
    float acc[4][4];
#pragma unroll
    for (int r = 0; r < 4; ++r)
#pragma unroll
        for (int c = 0; c < 4; ++c) acc[r][c] = 0.f;
    float ksloc = 0.f;
    const size_t base = (size_t)b * SSEQ * D_MODEL + h * HD_;

    for (int s0 = chunk*512; s0 < chunk*512 + 512; s0 += 32) {
        const float4 k0v = *(const float4*)&K[base + (size_t)(s0+lrow)    * D_MODEL + lq];
        const float4 k1v = *(const float4*)&K[base + (size_t)(s0+lrow+16) * D_MODEL + lq];
        const float4 v0v = *(const float4*)&V[base + (size_t)(s0+lrow)    * D_MODEL + lq];
        const float4 v1v = *(const float4*)&V[base + (size_t)(s0+lrow+16) * D_MODEL + lq];
        __syncthreads();
        *(float4*)&ks[lrow][lq]    = k0v;
        *(float4*)&ks[lrow+16][lq] = k1v;
        *(float4*)&vs[lrow][lq]    = v0v;
        *(float4*)&vs[lrow+16][lq] = v1v;
        __syncthreads();
#pragma unroll
        for (int s = 0; s < 32; ++s) {
            const float4 ka = *(const float4*)&ks[s][ty*4];
            const float4 vb = *(const float4*)&vs[s][tx*4];
            const float av[4] = {ka.x,ka.y,ka.z,ka.w};
            const float bv[4] = {vb.x,vb.y,vb.z,vb.w};
#pragma unroll
            for (int r = 0; r < 4; ++r)
#pragma unroll
                for (int c = 0; c < 4; ++c)
                    acc[r][c] = fmaf(av[r], bv[c], acc[r][c]);
        }
        if (tid < 64) {
#pragma unroll
            for (int s = 0; s < 32; ++s) ksloc += ks[s][tid];
        }
    }
    float* kvb = kv + ((size_t)((i_idx*B_ + b)*NH + h) << 12);
#pragma unroll
    for (int r = 0; r < 4; ++r)
#pragma unroll
        for (int c = 0; c < 4; ++c)
            atomicAdd(&kvb[(ty*4+r)*HD_ + tx*4+c], acc[r][c]);
    if (tid < 64)
        atomicAdd(&ksum[(size_t)((i_idx*B_ + b)*NH + h)*HD_ + tid], ksloc);
}

// In-place: Q[row, h*64+e] = (q + sum_i (q@kv_i)*dinv_i)/3 per head tile of 128 rows
__global__ __launch_bounds__(256)
void combine_kernel(float* __restrict__ Q, const float* __restrict__ kv,
                    const float* __restrict__ ksum)
{
    const int m0 = blockIdx.x * 128;
    const int h  = blockIdx.y;
    const int b  = m0 >> 13;            // NSEQ = 8192
    __shared__ __align__(16) float Qt[64][128];   // transposed q tile
    __shared__ __align__(16) float Bs[64][68];
    __shared__ float sk[NUM_I][64];
    __shared__ float dinv[NUM_I][128];
    const int tid = threadIdx.x;
    const int tx = tid & 15, ty = tid >> 4;

#pragma unroll
    for (int it = 0; it < 8; ++it) {
        const int j = tid + it*256;
        const int row = j >> 4;
        const int q4  = (j & 15) << 2;
        const float4 g = *(const float4*)&Q[(size_t)(m0+row)*D_MODEL + h*HD_ + q4];
        Qt[q4+0][row] = g.x; Qt[q4+1][row] = g.y; Qt[q4+2][row] = g.z; Qt[q4+3][row] = g.w;
    }
    if (tid < NUM_I*64) {
        const int i = tid >> 6, d = tid & 63;
        sk[i][d] = ksum[(size_t)((i*B_ + b)*NH + h)*HD_ + d];
    }
    __syncthreads();
    for (int idx = tid; idx < NUM_I*128; idx += 256) {
        const int i = idx >> 7, row = idx & 127;
        float dsum = 0.f;
#pragma unroll
        for (int dd = 0; dd < 64; ++dd) dsum += Qt[dd][row] * sk[i][dd];
        dinv[i][row] = 1.f / dsum;
    }

    float accO[8][4];
#pragma unroll
    for (int r = 0; r < 8; ++r)
#pragma unroll
        for (int c = 0; c < 4; ++c) accO[r][c] = 0.f;

    for (int i = 0; i < NUM_I; ++i) {
        const float* kvb = kv + ((size_t)((i*B_ + b)*NH + h) << 12);
        __syncthreads();   // prev compute done (and dinv ready on i=0) before Bs overwrite
#pragma unroll
        for (int it = 0; it < 4; ++it) {
            const int j = tid + it*256;
            *(float4*)&Bs[j >> 4][(j & 15) << 2] = *(const float4*)&kvb[(size_t)j << 2];
        }
        __syncthreads();
        float part[8][4];
#pragma unroll
        for (int r = 0; r < 8; ++r)
#pragma unroll
            for (int c = 0; c < 4; ++c) part[r][c] = 0.f;
#pragma unroll
        for (int kk = 0; kk < 64; ++kk) {
            const float4 fa0 = *(const float4*)&Qt[kk][ty*8];
            const float4 fa1 = *(const float4*)&Qt[kk][ty*8+4];
            const float4 fb  = *(const float4*)&Bs[kk][tx*4];
            const float av[8] = {fa0.x,fa0.y,fa0.z,fa0.w,fa1.x,fa1.y,fa1.z,fa1.w};
            const float bv[4] = {fb.x,fb.y,fb.z,fb.w};
#pragma unroll
            for (int r = 0; r < 8; ++r)
#pragma unroll
                for (int c = 0; c < 4; ++c)
                    part[r][c] = fmaf(av[r], bv[c], part[r][c]);
        }
#pragma unroll
        for (int r = 0; r < 8; ++r) {
            const float dv = dinv[i][ty*8 + r];
#pragma unroll
            for (int c = 0; c < 4; ++c) accO[r][c] = fmaf(part[r][c], dv, accO[r][c]);
        }
    }
    const float inv3 = 1.f / 3.f;
#pragma unroll
    for (int r = 0; r < 8; ++r) {
        const int row = ty*8 + r;
        float4 o;
        o.x = (Qt[tx*4+0][row] + accO[r][0]) * inv3;
        o.y = (Qt[tx*4+1][row] + accO[r][1]) * inv3;
        o.z = (Qt[tx*4+2][row] + accO[r][2]) * inv3;
        o.w = (Qt[tx*4+3][row] + accO[r][3]) * inv3;
        *(float4*)&Q[(size_t)(m0+row)*D_MODEL + h*HD_ + tx*4] = o;
    }
}

extern "C" void kernel_launch(void* const* d_in, const int* in_sizes, int n_in,
                              void* d_out, int out_size, void* d_ws, size_t ws_size,
                              hipStream_t stream)
{
    const float* x      = (const float*)d_in[0];
    const float* emb[3] = {(const float*)d_in[1], (const float*)d_in[2], (const float*)d_in[3]};
    const float* Wq = (const float*)d_in[4];
    const float* bq = (const float*)d_in[5];
    const float* Wk = (const float*)d_in[6];
    const float* bk = (const float*)d_in[7];
    const float* Wv = (const float*)d_in[8];
    const float* bv = (const float*)d_in[9];
    const float* Wo = (const float*)d_in[10];
    const float* bo = (const float*)d_in[11];
    const int* mask[3] = {(const int*)d_in[12], (const int*)d_in[13], (const int*)d_in[14]};
    float* out = (float*)d_out;

    float* ws   = (float*)d_ws;
    float* q    = ws + Q_OFF;
    float* kbuf = ws + K_OFF;
    float* vbuf = ws + V_OFF;
    float* kv   = ws + KV_OFF;
    float* ksum = ws + KS_OFF;
    int*   flag = (int*)(ws + FLAG_OFF);

    mask_mode_kernel<<<1, 256, 0, stream>>>(mask[0], flag);
    hipMemsetAsync(kv, 0, (size_t)(NUM_I*B_*NH*HD_*HD_ + NUM_I*B_*NH*HD_) * sizeof(float), stream);

    const dim3 gq(B_*NSEQ/128, D_MODEL/64);   // (256, 8)
    const dim3 gk(B_*SSEQ/128, D_MODEL/64);   // (128, 8)

    proj_kernel<1><<<gq, 256, 0, stream>>>(x, Wq, bq, nullptr, nullptr, q);
    for (int i = 0; i < NUM_I; ++i) {
        proj_kernel<2><<<gk, 256, 0, stream>>>(emb[i], Wk + (size_t)i*D_MODEL*D_MODEL,
                                               bk + (size_t)i*D_MODEL, mask[i], flag, kbuf);
        proj_kernel<0><<<gk, 256, 0, stream>>>(emb[i], Wv + (size_t)i*D_MODEL*D_MODEL,
                                               bv + (size_t)i*D_MODEL, nullptr, nullptr, vbuf);
        kv_accum_kernel<<<dim3(8, NH, B_), 256, 0, stream>>>(kbuf, vbuf, kv, ksum, i);
    }
    combine_kernel<<<dim3(B_*NSEQ/128, NH), 256, 0, stream>>>(q, kv, ksum);
    proj_kernel<0><<<gq, 256, 0, stream>>>(q, Wo, bo, nullptr, nullptr, out);
}

// Round 2
// 712.783 us; speedup vs baseline: 2.1512x; 2.1512x over previous
//
#include <hip/hip_runtime.h>

#define D_MODEL 512
#define NH 8
#define HD_ 64
#define NUM_I 3
#define B_ 4
#define NSEQ 8192
#define SSEQ 4096

typedef __attribute__((ext_vector_type(8))) short short8;
typedef __attribute__((ext_vector_type(4))) float floatx4;

// workspace layout (float-element offsets)
static constexpr size_t Q_OFF    = 0;            // q bf16: 16,777,216 bf16 = 8,388,608 float slots
static constexpr size_t KBUF_OFF = 8388608;      // k fp32 (8,388,608); later reused as q2 bf16
static constexpr size_t VBUF_OFF = 16777216;     // v fp32 (8,388,608); xb bf16 overlaps (used before v)
static constexpr size_t EMBB_OFF = 25165824;     // emb bf16: 8,388,608 bf16 = 4,194,304 slots
static constexpr size_t WB_OFF   = 29360128;     // weights bf16: 2,097,152 bf16 = 1,048,576 slots
static constexpr size_t KV_OFF   = 30408704;     // 393,216 fp32
static constexpr size_t KS_OFF   = 30801920;     // 6,144 fp32
static constexpr size_t FLAG_OFF = 30808064;     // 1 int

__device__ __forceinline__ float bf2f(unsigned short u) {
    union { unsigned i; float f; } v; v.i = ((unsigned)u) << 16; return v.f;
}
__device__ __forceinline__ unsigned short f2bf(float f) {
    union { float f; unsigned i; } v; v.f = f;
    unsigned r = v.i + 0x7fffu + ((v.i >> 16) & 1u);
    return (unsigned short)(r >> 16);
}

__device__ __forceinline__ void gld16(const void* g, void* l) {
    __builtin_amdgcn_global_load_lds((const __attribute__((address_space(1))) void*)g,
                                     (__attribute__((address_space(3))) void*)l, 16, 0, 0);
}

// Detect mask storage: int32 (every word 0/1) vs packed numpy bool bytes.
__global__ void mask_mode_kernel(const int* __restrict__ m, int* __restrict__ flag)
{
    __shared__ int any;
    if (threadIdx.x == 0) any = 0;
    __syncthreads();
    const unsigned v = (unsigned)m[threadIdx.x];
    if (v > 1u) atomicOr(&any, 1);
    __syncthreads();
    if (threadIdx.x == 0) *flag = any;
}

// fp32 -> bf16 pack, 8 elems/thread
__global__ __launch_bounds__(256)
void f2bf_kernel(const float* __restrict__ in, unsigned short* __restrict__ out, int n8)
{
    const int i = blockIdx.x * 256 + threadIdx.x;
    if (i >= n8) return;
    const float4 a = ((const float4*)in)[2*i];
    const float4 b = ((const float4*)in)[2*i + 1];
    short8 r;
    r[0] = (short)f2bf(a.x); r[1] = (short)f2bf(a.y);
    r[2] = (short)f2bf(a.z); r[3] = (short)f2bf(a.w);
    r[4] = (short)f2bf(b.x); r[5] = (short)f2bf(b.y);
    r[6] = (short)f2bf(b.z); r[7] = (short)f2bf(b.w);
    ((short8*)out)[i] = r;
}

// C[m][n] = sum_k A[m][k]*W[n][k] + bias[n], bf16 MFMA.
// EPI: 0 none, 1 softmax per 64-col head, 2 softmax+row-mask.
// BF16OUT: store bf16 instead of fp32.
template<int EPI, bool BF16OUT>
__global__ __launch_bounds__(256)
void proj_mfma(const unsigned short* __restrict__ A, const unsigned short* __restrict__ W,
               const float* __restrict__ bias, const int* __restrict__ mask,
               const int* __restrict__ maskmode, void* __restrict__ Cv)
{
    // granule layout: LDS granule G (16B = 8 bf16) at shorts G*8; G = kslot*128 + row
    __shared__ short As[4096];
    __shared__ short Bs[4096];
    const int tid  = threadIdx.x;
    const int wid  = tid >> 6, lane = tid & 63;
    const int wm   = wid & 1,  wn   = wid >> 1;
    const int l15  = lane & 15, lq  = lane >> 4;
    const int m0   = blockIdx.x * 128;
    const int n0   = blockIdx.y * 128;

    floatx4 acc[4][4] = {};

    // staging: thread t owns granules t and t+256 (same row, kslot and kslot+2)
    const int srow = tid & 127;
    const int sks  = tid >> 7;
    const unsigned short* Ag = A + (size_t)(m0 + srow) * D_MODEL + sks * 8;
    const unsigned short* Wg = W + (size_t)(n0 + srow) * D_MODEL + sks * 8;
    short* AsW = As + wid * 512;   // wave-uniform LDS base (HW adds lane*16B)
    short* BsW = Bs + wid * 512;

    const int aoff = (lq * 128 + wm * 64 + l15) * 8;
    const int boff = (lq * 128 + wn * 64 + l15) * 8;

    for (int k0 = 0; k0 < D_MODEL; k0 += 32) {
        __syncthreads();
        gld16(Ag + k0,      AsW);
        gld16(Ag + k0 + 16, AsW + 2048);
        gld16(Wg + k0,      BsW);
        gld16(Wg + k0 + 16, BsW + 2048);
        __syncthreads();
        short8 af[4], bfv[4];
#pragma unroll
        for (int mt = 0; mt < 4; ++mt) af[mt]  = *(const short8*)&As[aoff + mt * 128];
#pragma unroll
        for (int nt = 0; nt < 4; ++nt) bfv[nt] = *(const short8*)&Bs[boff + nt * 128];
#pragma unroll
        for (int mt = 0; mt < 4; ++mt)
#pragma unroll
            for (int nt = 0; nt < 4; ++nt)
                acc[mt][nt] = __builtin_amdgcn_mfma_f32_16x16x32_bf16(af[mt], bfv[nt], acc[mt][nt], 0, 0, 0);
    }

    // bias
    float bl[4];
#pragma unroll
    for (int nt = 0; nt < 4; ++nt) bl[nt] = bias[n0 + wn * 64 + nt * 16 + l15];
#pragma unroll
    for (int mt = 0; mt < 4; ++mt)
#pragma unroll
        for (int nt = 0; nt < 4; ++nt)
#pragma unroll
            for (int r = 0; r < 4; ++r) acc[mt][nt][r] += bl[nt];

    if (EPI >= 1) {
        // softmax over this wave's 64 cols (one head): per (mt, r) row
#pragma unroll
        for (int mt = 0; mt < 4; ++mt)
#pragma unroll
            for (int r = 0; r < 4; ++r) {
                float mx = fmaxf(fmaxf(acc[mt][0][r], acc[mt][1][r]),
                                 fmaxf(acc[mt][2][r], acc[mt][3][r]));
#pragma unroll
                for (int off = 1; off < 16; off <<= 1) mx = fmaxf(mx, __shfl_xor(mx, off));
                float s = 0.f;
#pragma unroll
                for (int nt = 0; nt < 4; ++nt) {
                    const float e = __expf(acc[mt][nt][r] - mx);
                    acc[mt][nt][r] = e; s += e;
                }
#pragma unroll
                for (int off = 1; off < 16; off <<= 1) s += __shfl_xor(s, off);
                const float inv = 1.f / s;
#pragma unroll
                for (int nt = 0; nt < 4; ++nt) acc[mt][nt][r] *= inv;
            }
    }
    if (EPI == 2) {
        const int bytemode = *maskmode;
#pragma unroll
        for (int mt = 0; mt < 4; ++mt)
#pragma unroll
            for (int r = 0; r < 4; ++r) {
                const int grow = m0 + wm * 64 + mt * 16 + lq * 4 + r;
                const bool keep = bytemode ? (((const unsigned char*)mask)[grow] != 0)
                                           : (mask[grow] != 0);
                if (!keep) {
#pragma unroll
                    for (int nt = 0; nt < 4; ++nt) acc[mt][nt][r] = 0.f;
                }
            }
    }

#pragma unroll
    for (int mt = 0; mt < 4; ++mt)
#pragma unroll
        for (int r = 0; r < 4; ++r) {
            const size_t row = m0 + wm * 64 + mt * 16 + lq * 4 + r;
#pragma unroll
            for (int nt = 0; nt < 4; ++nt) {
                const int col = n0 + wn * 64 + nt * 16 + l15;
                if (BF16OUT)
                    ((unsigned short*)Cv)[row * D_MODEL + col] = f2bf(acc[mt][nt][r]);
                else
                    ((float*)Cv)[row * D_MODEL + col] = acc[mt][nt][r];
            }
        }
}

// kv[i,b,h,d,e] += sum_s k[s,d]*v[s,e]; ksum[i,b,h,d] += sum_s k[s,d]  (split over s-chunks)
__global__ __launch_bounds__(256)
void kv_accum_kernel(const float* __restrict__ K, const float* __restrict__ V,
                     float* __restrict__ kv, float* __restrict__ ksum, int i_idx)
{
    const int chunk = blockIdx.x;  // 0..7 (512 s each)
    const int h = blockIdx.y;
    const int b = blockIdx.z;
    __shared__ __align__(16) float ks[32][68];
    __shared__ __align__(16) float vs[32][68];
    const int tid = threadIdx.x;
    const int tx = tid & 15, ty = tid >> 4;
    const int lrow = tid >> 4;
    const int lq = (tid & 15) << 2;
    float acc[4][4];
#pragma unroll
    for (int r = 0; r < 4; ++r)
#pragma unroll
        for (int c = 0; c < 4; ++c) acc[r][c] = 0.f;
    float ksloc = 0.f;
    const size_t base = (size_t)b * SSEQ * D_MODEL + h * HD_;

    for (int s0 = chunk*512; s0 < chunk*512 + 512; s0 += 32) {
        const float4 k0v = *(const float4*)&K[base + (size_t)(s0+lrow)    * D_MODEL + lq];
        const float4 k1v = *(const float4*)&K[base + (size_t)(s0+lrow+16) * D_MODEL + lq];
        const float4 v0v = *(const float4*)&V[base + (size_t)(s0+lrow)    * D_MODEL + lq];
        const float4 v1v = *(const float4*)&V[base + (size_t)(s0+lrow+16) * D_MODEL + lq];
        __syncthreads();
        *(float4*)&ks[lrow][lq]    = k0v;
        *(float4*)&ks[lrow+16][lq] = k1v;
        *(float4*)&vs[lrow][lq]    = v0v;
        *(float4*)&vs[lrow+16][lq] = v1v;
        __syncthreads();
#pragma unroll
        for (int s = 0; s < 32; ++s) {
            const float4 ka = *(const float4*)&ks[s][ty*4];
            const float4 vb = *(const float4*)&vs[s][tx*4];
            const float av[4] = {ka.x,ka.y,ka.z,ka.w};
            const float bv[4] = {vb.x,vb.y,vb.z,vb.w};
#pragma unroll
            for (int r = 0; r < 4; ++r)
#pragma unroll
                for (int c = 0; c < 4; ++c)
                    acc[r][c] = fmaf(av[r], bv[c], acc[r][c]);
        }
        if (tid < 64) {
#pragma unroll
            for (int s = 0; s < 32; ++s) ksloc += ks[s][tid];
        }
    }
    float* kvb = kv + ((size_t)((i_idx*B_ + b)*NH + h) << 12);
#pragma unroll
    for (int r = 0; r < 4; ++r)
#pragma unroll
        for (int c = 0; c < 4; ++c)
            atomicAdd(&kvb[(ty*4+r)*HD_ + tx*4+c], acc[r][c]);
    if (tid < 64)
        atomicAdd(&ksum[(size_t)((i_idx*B_ + b)*NH + h)*HD_ + tid], ksloc);
}

// Qo[row, h*64+e] = (q + sum_i (q@kv_i)*dinv_i)/3, q bf16 in, bf16 out
__global__ __launch_bounds__(256)
void combine_kernel(const unsigned short* __restrict__ Q, const float* __restrict__ kv,
                    const float* __restrict__ ksum, unsigned short* __restrict__ Qo)
{
    const int m0 = blockIdx.x * 128;
    const int h  = blockIdx.y;
    const int b  = m0 >> 13;            // NSEQ = 8192
    __shared__ __align__(16) float Qt[64][128];   // transposed q tile
    __shared__ __align__(16) float Bs[64][68];
    __shared__ float sk[NUM_I][64];
    __shared__ float dinv[NUM_I][128];
    const int tid = threadIdx.x;
    const int tx = tid & 15, ty = tid >> 4;

#pragma unroll
    for (int it = 0; it < 4; ++it) {
        const int j = tid + it*256;          // 1024 granules of 8 bf16
        const int row = j >> 3;
        const int c0  = (j & 7) << 3;
        const short8 g = *(const short8*)&Q[(size_t)(m0+row)*D_MODEL + h*HD_ + c0];
#pragma unroll
        for (int t = 0; t < 8; ++t) Qt[c0+t][row] = bf2f((unsigned short)g[t]);
    }
    if (tid < NUM_I*64) {
        const int i = tid >> 6, d = tid & 63;
        sk[i][d] = ksum[(size_t)((i*B_ + b)*NH + h)*HD_ + d];
    }
    __syncthreads();
    for (int idx = tid; idx < NUM_I*128; idx += 256) {
        const int i = idx >> 7, row = idx & 127;
        float dsum = 0.f;
#pragma unroll
        for (int dd = 0; dd < 64; ++dd) dsum += Qt[dd][row] * sk[i][dd];
        dinv[i][row] = 1.f / dsum;
    }

    float accO[8][4];
#pragma unroll
    for (int r = 0; r < 8; ++r)
#pragma unroll
        for (int c = 0; c < 4; ++c) accO[r][c] = 0.f;

    for (int i = 0; i < NUM_I; ++i) {
        const float* kvb = kv + ((size_t)((i*B_ + b)*NH + h) << 12);
        __syncthreads();
#pragma unroll
        for (int it = 0; it < 4; ++it) {
            const int j = tid + it*256;
            *(float4*)&Bs[j >> 4][(j & 15) << 2] = *(const float4*)&kvb[(size_t)j << 2];
        }
        __syncthreads();
        float part[8][4];
#pragma unroll
        for (int r = 0; r < 8; ++r)
#pragma unroll
            for (int c = 0; c < 4; ++c) part[r][c] = 0.f;
#pragma unroll
        for (int kk = 0; kk < 64; ++kk) {
            const float4 fa0 = *(const float4*)&Qt[kk][ty*8];
            const float4 fa1 = *(const float4*)&Qt[kk][ty*8+4];
            const float4 fb  = *(const float4*)&Bs[kk][tx*4];
            const float av[8] = {fa0.x,fa0.y,fa0.z,fa0.w,fa1.x,fa1.y,fa1.z,fa1.w};
            const float bv[4] = {fb.x,fb.y,fb.z,fb.w};
#pragma unroll
            for (int r = 0; r < 8; ++r)
#pragma unroll
                for (int c = 0; c < 4; ++c)
                    part[r][c] = fmaf(av[r], bv[c], part[r][c]);
        }
#pragma unroll
        for (int r = 0; r < 8; ++r) {
            const float dv = dinv[i][ty*8 + r];
#pragma unroll
            for (int c = 0; c < 4; ++c) accO[r][c] = fmaf(part[r][c], dv, accO[r][c]);
        }
    }
    const float inv3 = 1.f / 3.f;
#pragma unroll
    for (int r = 0; r < 8; ++r) {
        const int row = ty*8 + r;
        ushort4 o;
        o.x = f2bf((Qt[tx*4+0][row] + accO[r][0]) * inv3);
        o.y = f2bf((Qt[tx*4+1][row] + accO[r][1]) * inv3);
        o.z = f2bf((Qt[tx*4+2][row] + accO[r][2]) * inv3);
        o.w = f2bf((Qt[tx*4+3][row] + accO[r][3]) * inv3);
        *(ushort4*)&Qo[(size_t)(m0+row)*D_MODEL + h*HD_ + tx*4] = o;
    }
}

extern "C" void kernel_launch(void* const* d_in, const int* in_sizes, int n_in,
                              void* d_out, int out_size, void* d_ws, size_t ws_size,
                              hipStream_t stream)
{
    const float* x      = (const float*)d_in[0];
    const float* emb[3] = {(const float*)d_in[1], (const float*)d_in[2], (const float*)d_in[3]};
    const float* Wq = (const float*)d_in[4];
    const float* bq = (const float*)d_in[5];
    const float* Wk = (const float*)d_in[6];
    const float* bk = (const float*)d_in[7];
    const float* Wv = (const float*)d_in[8];
    const float* bv = (const float*)d_in[9];
    const float* Wo = (const float*)d_in[10];
    const float* bo = (const float*)d_in[11];
    const int* mask[3] = {(const int*)d_in[12], (const int*)d_in[13], (const int*)d_in[14]};
    float* out = (float*)d_out;

    float* ws = (float*)d_ws;
    unsigned short* qb   = (unsigned short*)(ws + Q_OFF);
    float*          kbuf = ws + KBUF_OFF;
    float*          vbuf = ws + VBUF_OFF;
    unsigned short* xb   = (unsigned short*)(ws + VBUF_OFF);   // dead before vbuf written
    unsigned short* embb = (unsigned short*)(ws + EMBB_OFF);
    unsigned short* wb   = (unsigned short*)(ws + WB_OFF);
    unsigned short* wqb  = wb;
    unsigned short* wkb  = wb + 262144;
    unsigned short* wvb  = wb + 1048576;
    unsigned short* wob  = wb + 1835008;
    unsigned short* q2b  = (unsigned short*)(ws + KBUF_OFF);   // reuses kbuf after last kv_accum
    float* kv   = ws + KV_OFF;
    float* ksum = ws + KS_OFF;
    int*   flag = (int*)(ws + FLAG_OFF);

    mask_mode_kernel<<<1, 256, 0, stream>>>(mask[0], flag);
    hipMemsetAsync(kv, 0, (size_t)(NUM_I*B_*NH*HD_*HD_ + NUM_I*B_*NH*HD_) * sizeof(float), stream);

    // conversions
    f2bf_kernel<<<8192, 256, 0, stream>>>(x,  xb,  2097152);
    f2bf_kernel<<<128,  256, 0, stream>>>(Wq, wqb, 32768);
    f2bf_kernel<<<384,  256, 0, stream>>>(Wk, wkb, 98304);
    f2bf_kernel<<<384,  256, 0, stream>>>(Wv, wvb, 98304);
    f2bf_kernel<<<128,  256, 0, stream>>>(Wo, wob, 32768);

    const dim3 gq(B_*NSEQ/128, D_MODEL/128);   // (256, 4)
    const dim3 gk(B_*SSEQ/128, D_MODEL/128);   // (128, 4)

    proj_mfma<1, true ><<<gq, 256, 0, stream>>>(xb, wqb, bq, nullptr, nullptr, qb);
    for (int i = 0; i < NUM_I; ++i) {
        f2bf_kernel<<<4096, 256, 0, stream>>>(emb[i], embb, 1048576);
        proj_mfma<2, false><<<gk, 256, 0, stream>>>(embb, wkb + (size_t)i*262144,
                                                    bk + (size_t)i*D_MODEL, mask[i], flag, kbuf);
        proj_mfma<0, false><<<gk, 256, 0, stream>>>(embb, wvb + (size_t)i*262144,
                                                    bv + (size_t)i*D_MODEL, nullptr, nullptr, vbuf);
        kv_accum_kernel<<<dim3(8, NH, B_), 256, 0, stream>>>(kbuf, vbuf, kv, ksum, i);
    }
    combine_kernel<<<dim3(B_*NSEQ/128, NH), 256, 0, stream>>>(qb, kv, ksum, q2b);
    proj_mfma<0, false><<<gq, 256, 0, stream>>>(q2b, wob, bo, nullptr, nullptr, out);
}

// Round 3
// 581.259 us; speedup vs baseline: 2.6380x; 1.2263x over previous
//
#include <hip/hip_runtime.h>

#define D_MODEL 512
#define NH 8
#define HD_ 64
#define NUM_I 3
#define B_ 4
#define NSEQ 8192
#define SSEQ 4096

typedef __attribute__((ext_vector_type(8))) short short8;
typedef __attribute__((ext_vector_type(4))) float floatx4;

// workspace layout (float-element offsets)
static constexpr size_t Q_OFF    = 0;          // qb bf16 (8.4M slots)
static constexpr size_t KT_OFF   = 8388608;    // kT bf16 (4.2M slots); xb & q2b alias [8388608,16777216)
static constexpr size_t VT_OFF   = 12582912;   // vT bf16 (4.2M slots)
static constexpr size_t XB_OFF   = 8388608;    // xb bf16 (dead before kT written)
static constexpr size_t Q2_OFF   = 8388608;    // q2 bf16 (written after kv_accum done)
static constexpr size_t EMBB_OFF = 16777216;   // emb bf16 (4.2M slots)
static constexpr size_t WB_OFF   = 20971520;   // weights bf16 (1.05M slots)
static constexpr size_t KV_OFF   = 22020096;   // kvT fp32 393216
static constexpr size_t KS_OFF   = 22413312;   // ksum fp32 6144  (contiguous w/ KV for one memset)
static constexpr size_t KVB_OFF  = 22419456;   // kvT bf16 196608 slots
static constexpr size_t FLAG_OFF = 22616064;   // 1 int

__device__ __forceinline__ float bf2f(unsigned short u) {
    union { unsigned i; float f; } v; v.i = ((unsigned)u) << 16; return v.f;
}
__device__ __forceinline__ unsigned short f2bf(float f) {
    union { float f; unsigned i; } v; v.f = f;
    unsigned r = v.i + 0x7fffu + ((v.i >> 16) & 1u);
    return (unsigned short)(r >> 16);
}
__device__ __forceinline__ void gld16(const void* g, void* l) {
    __builtin_amdgcn_global_load_lds((const __attribute__((address_space(1))) void*)g,
                                     (__attribute__((address_space(3))) void*)l, 16, 0, 0);
}

// Detect mask storage: int32 words (0/1) vs packed numpy bool bytes.
__global__ void mask_mode_kernel(const int* __restrict__ m, int* __restrict__ flag)
{
    __shared__ int any;
    if (threadIdx.x == 0) any = 0;
    __syncthreads();
    const unsigned v = (unsigned)m[threadIdx.x];
    if (v > 1u) atomicOr(&any, 1);
    __syncthreads();
    if (threadIdx.x == 0) *flag = any;
}

// fp32 -> bf16 pack, 8 elems/thread
__global__ __launch_bounds__(256)
void f2bf_kernel(const float* __restrict__ in, unsigned short* __restrict__ out, int n8)
{
    const int i = blockIdx.x * 256 + threadIdx.x;
    if (i >= n8) return;
    const float4 a = ((const float4*)in)[2*i];
    const float4 b = ((const float4*)in)[2*i + 1];
    short8 r;
    r[0] = (short)f2bf(a.x); r[1] = (short)f2bf(a.y);
    r[2] = (short)f2bf(a.z); r[3] = (short)f2bf(a.w);
    r[4] = (short)f2bf(b.x); r[5] = (short)f2bf(b.y);
    r[6] = (short)f2bf(b.z); r[7] = (short)f2bf(b.w);
    ((short8*)out)[i] = r;
}

// C[m][n] = sum_k A[m][k]*W[n][k] + bias[n], bf16 MFMA.
// EPI: 0 none, 1 softmax per 64-col head, 2 softmax+row-mask.
// OUT: 0 fp32 row-major, 1 bf16 row-major, 2 bf16 transposed per head -> Cv[(b*NH+h)*64+d][SSEQ]
template<int EPI, int OUT>
__global__ __launch_bounds__(256)
void proj_mfma(const unsigned short* __restrict__ A, const unsigned short* __restrict__ W,
               const float* __restrict__ bias, const int* __restrict__ mask,
               const int* __restrict__ maskmode, void* __restrict__ Cv)
{
    __shared__ short smem[(OUT == 2) ? 18432 : 8192];
    short* As = smem;
    short* Bs = smem + 4096;
    const int tid  = threadIdx.x;
    const int wid  = tid >> 6, lane = tid & 63;
    const int wm   = wid & 1,  wn   = wid >> 1;
    const int l15  = lane & 15, lq  = lane >> 4;
    const int m0   = blockIdx.x * 128;
    const int n0   = blockIdx.y * 128;

    floatx4 acc[4][4] = {};

    const int srow = tid & 127;
    const int sks  = tid >> 7;
    const unsigned short* Ag = A + (size_t)(m0 + srow) * D_MODEL + sks * 8;
    const unsigned short* Wg = W + (size_t)(n0 + srow) * D_MODEL + sks * 8;
    short* AsW = As + wid * 512;   // wave-uniform LDS base
    short* BsW = Bs + wid * 512;

    const int aoff = (lq * 128 + wm * 64 + l15) * 8;
    const int boff = (lq * 128 + wn * 64 + l15) * 8;

    for (int k0 = 0; k0 < D_MODEL; k0 += 32) {
        __syncthreads();
        gld16(Ag + k0,      AsW);
        gld16(Ag + k0 + 16, AsW + 2048);
        gld16(Wg + k0,      BsW);
        gld16(Wg + k0 + 16, BsW + 2048);
        __syncthreads();
        short8 af[4], bfv[4];
#pragma unroll
        for (int mt = 0; mt < 4; ++mt) af[mt]  = *(const short8*)&As[aoff + mt * 128];
#pragma unroll
        for (int nt = 0; nt < 4; ++nt) bfv[nt] = *(const short8*)&Bs[boff + nt * 128];
#pragma unroll
        for (int mt = 0; mt < 4; ++mt)
#pragma unroll
            for (int nt = 0; nt < 4; ++nt)
                acc[mt][nt] = __builtin_amdgcn_mfma_f32_16x16x32_bf16(af[mt], bfv[nt], acc[mt][nt], 0, 0, 0);
    }

    float bl[4];
#pragma unroll
    for (int nt = 0; nt < 4; ++nt) bl[nt] = bias[n0 + wn * 64 + nt * 16 + l15];
#pragma unroll
    for (int mt = 0; mt < 4; ++mt)
#pragma unroll
        for (int nt = 0; nt < 4; ++nt)
#pragma unroll
            for (int r = 0; r < 4; ++r) acc[mt][nt][r] += bl[nt];

    if (EPI >= 1) {
#pragma unroll
        for (int mt = 0; mt < 4; ++mt)
#pragma unroll
            for (int r = 0; r < 4; ++r) {
                float mx = fmaxf(fmaxf(acc[mt][0][r], acc[mt][1][r]),
                                 fmaxf(acc[mt][2][r], acc[mt][3][r]));
#pragma unroll
                for (int off = 1; off < 16; off <<= 1) mx = fmaxf(mx, __shfl_xor(mx, off));
                float s = 0.f;
#pragma unroll
                for (int nt = 0; nt < 4; ++nt) {
                    const float e = __expf(acc[mt][nt][r] - mx);
                    acc[mt][nt][r] = e; s += e;
                }
#pragma unroll
                for (int off = 1; off < 16; off <<= 1) s += __shfl_xor(s, off);
                const float inv = 1.f / s;
#pragma unroll
                for (int nt = 0; nt < 4; ++nt) acc[mt][nt][r] *= inv;
            }
    }
    if (EPI == 2) {
        const int bytemode = *maskmode;
#pragma unroll
        for (int mt = 0; mt < 4; ++mt)
#pragma unroll
            for (int r = 0; r < 4; ++r) {
                const int grow = m0 + wm * 64 + mt * 16 + lq * 4 + r;
                const bool keep = bytemode ? (((const unsigned char*)mask)[grow] != 0)
                                           : (mask[grow] != 0);
                if (!keep) {
#pragma unroll
                    for (int nt = 0; nt < 4; ++nt) acc[mt][nt][r] = 0.f;
                }
            }
    }

    if (OUT == 2) {
        // transpose wave's 64x64 tile through LDS, store [d][s] rows (s-contiguous)
        __syncthreads();                  // all frag reads of As/Bs done
        short* tw = smem + wid * 4608;    // 64 x 72 shorts per wave
#pragma unroll
        for (int mt = 0; mt < 4; ++mt)
#pragma unroll
            for (int nt = 0; nt < 4; ++nt) {
                ushort4 p;
                p.x = f2bf(acc[mt][nt][0]); p.y = f2bf(acc[mt][nt][1]);
                p.z = f2bf(acc[mt][nt][2]); p.w = f2bf(acc[mt][nt][3]);
                *(ushort4*)&tw[(nt*16 + l15)*72 + mt*16 + lq*4] = p;
            }
        __syncthreads();
        const int b_idx = m0 >> 12;            // SSEQ = 4096 rows per batch
        const int s_base = (m0 & 4095) + wm * 64;
        const int h = (n0 >> 6) + wn;
        unsigned short* outp = (unsigned short*)Cv +
            ((size_t)(b_idx * NH + h) * 64 + lane) * SSEQ + s_base;
        const short* src = &tw[lane * 72];
#pragma unroll
        for (int sc = 0; sc < 8; ++sc)
            *(short8*)&outp[sc*8] = *(const short8*)&src[sc*8];
    } else {
#pragma unroll
        for (int mt = 0; mt < 4; ++mt)
#pragma unroll
            for (int r = 0; r < 4; ++r) {
                const size_t row = m0 + wm * 64 + mt * 16 + lq * 4 + r;
#pragma unroll
                for (int nt = 0; nt < 4; ++nt) {
                    const int col = n0 + wn * 64 + nt * 16 + l15;
                    if (OUT == 1)
                        ((unsigned short*)Cv)[row * D_MODEL + col] = f2bf(acc[mt][nt][r]);
                    else
                        ((float*)Cv)[row * D_MODEL + col] = acc[mt][nt][r];
                }
            }
    }
}

// kvT[e][d] += sum_s vT[e][s]*kT[d][s]; ksum[d] += sum_s kT[d][s].  MFMA, split-s.
__global__ __launch_bounds__(256)
void kv_accum_mfma(const unsigned short* __restrict__ kT, const unsigned short* __restrict__ vT,
                   float* __restrict__ kv, float* __restrict__ ksum, int i_idx)
{
    const int chunk = blockIdx.x;   // 0..7, 512 s each
    const int h = blockIdx.y, b = blockIdx.z;
    __shared__ short As[2048];      // vT tile: granule g = sub*64 + row(e), 8 s each
    __shared__ short Bs[2048];      // kT tile: granule g = sub*64 + row(d)
    const int tid = threadIdx.x;
    const int wid = tid >> 6, lane = tid & 63;
    const int wm  = wid & 1,  wn  = wid >> 1;
    const int l15 = lane & 15, lq = lane >> 4;

    const size_t base = (size_t)(b * NH + h) * 64 * SSEQ + chunk * 512;
    const int srow = tid & 63, ssub = tid >> 6;
    const unsigned short* Ag = vT + base + (size_t)srow * SSEQ + ssub * 8;
    const unsigned short* Bg = kT + base + (size_t)srow * SSEQ + ssub * 8;
    short* AsW = As + wid * 512;
    short* BsW = Bs + wid * 512;

    floatx4 acc[2][2] = {};
    floatx4 ks[2] = {};
    short8 ones;
#pragma unroll
    for (int j = 0; j < 8; ++j) ones[j] = (short)0x3F80;  // bf16 1.0

    const int aoff = (wm*32 + l15)*8;   // + mt*128 ; granule lq*64 + row -> shorts (lq*64+row)*8
    const int boff = (wn*32 + l15)*8;

    for (int k0 = 0; k0 < 512; k0 += 32) {
        __syncthreads();
        gld16(Ag + k0, AsW);
        gld16(Bg + k0, BsW);
        __syncthreads();
        short8 af[2], bfr[2];
#pragma unroll
        for (int mt = 0; mt < 2; ++mt) af[mt]  = *(const short8*)&As[lq*512 + aoff + mt*128];
#pragma unroll
        for (int nt = 0; nt < 2; ++nt) bfr[nt] = *(const short8*)&Bs[lq*512 + boff + nt*128];
#pragma unroll
        for (int mt = 0; mt < 2; ++mt)
#pragma unroll
            for (int nt = 0; nt < 2; ++nt)
                acc[mt][nt] = __builtin_amdgcn_mfma_f32_16x16x32_bf16(af[mt], bfr[nt], acc[mt][nt], 0, 0, 0);
        if (wm == 0) {
#pragma unroll
            for (int nt = 0; nt < 2; ++nt)
                ks[nt] = __builtin_amdgcn_mfma_f32_16x16x32_bf16(ones, bfr[nt], ks[nt], 0, 0, 0);
        }
    }
    float* kvb = kv + (size_t)((i_idx*B_ + b)*NH + h) * 4096;  // [e][d]
#pragma unroll
    for (int mt = 0; mt < 2; ++mt)
#pragma unroll
        for (int nt = 0; nt < 2; ++nt)
#pragma unroll
            for (int r = 0; r < 4; ++r) {
                const int e = wm*32 + mt*16 + lq*4 + r;
                const int d = wn*32 + nt*16 + l15;
                atomicAdd(&kvb[e*64 + d], acc[mt][nt][r]);
            }
    if (wm == 0 && lq == 0) {
        float* ksb = ksum + (size_t)((i_idx*B_ + b)*NH + h) * 64;
#pragma unroll
        for (int nt = 0; nt < 2; ++nt)
            atomicAdd(&ksb[wn*32 + nt*16 + l15], ks[nt][0]);
    }
}

// q2[row, h*64+e] = (q + sum_i (q@kv_i)*dinv_i)/3 ; q bf16, kvT bf16, MFMA
__global__ __launch_bounds__(256)
void combine_mfma(const unsigned short* __restrict__ Q, const unsigned short* __restrict__ kvT,
                  const float* __restrict__ ksum, unsigned short* __restrict__ Qo)
{
    const int m0 = blockIdx.x * 128;
    const int h  = blockIdx.y;
    const int b  = m0 >> 13;   // NSEQ = 8192
    __shared__ short qs[8192];             // granule g = c*128 + row, 8 d's each
    __shared__ float skl[NUM_I][64];
    __shared__ float dinv[NUM_I][128];
    const int tid = threadIdx.x;
    const int wid = tid >> 6, lane = tid & 63;
    const int l15 = lane & 15, lq = lane >> 4;

    const unsigned short* Qbase = Q + (size_t)m0 * D_MODEL + h * 64;
#pragma unroll
    for (int j = 0; j < 4; ++j) {
        const int g = tid + j * 256;
        const int row = g & 127, c = g >> 7;
        gld16(Qbase + (size_t)row * D_MODEL + c * 8, qs + (size_t)(wid*64 + j*256) * 8);
    }
    if (tid < NUM_I * 64) {
        const int i = tid >> 6, d = tid & 63;
        skl[i][d] = ksum[(size_t)((i*B_ + b)*NH + h) * 64 + d];
    }
    __syncthreads();
    for (int it = tid; it < NUM_I * 128; it += 256) {
        const int i = it >> 7, row = it & 127;
        float s = 0.f;
#pragma unroll
        for (int d = 0; d < 64; ++d)
            s += bf2f((unsigned short)qs[(d >> 3)*1024 + row*8 + (d & 7)]) * skl[i][d];
        dinv[i][row] = 1.f / s;
    }
    __syncthreads();

    // A-frags: rows wid*32 + mt*16, k = d
    short8 af[2][2];
#pragma unroll
    for (int mt = 0; mt < 2; ++mt)
#pragma unroll
        for (int ks = 0; ks < 2; ++ks)
            af[mt][ks] = *(const short8*)&qs[(ks*4 + lq)*1024 + (wid*32 + mt*16 + l15)*8];

    floatx4 accO[2][4] = {};
    for (int i = 0; i < NUM_I; ++i) {
        const unsigned short* kvb = kvT + (size_t)((i*B_ + b)*NH + h) * 4096;  // [e][d]
        short8 bfr[4][2];
#pragma unroll
        for (int nt = 0; nt < 4; ++nt)
#pragma unroll
            for (int ks = 0; ks < 2; ++ks)
                bfr[nt][ks] = *(const short8*)&kvb[(nt*16 + l15)*64 + ks*32 + lq*8];
#pragma unroll
        for (int mt = 0; mt < 2; ++mt)
#pragma unroll
            for (int nt = 0; nt < 4; ++nt) {
                floatx4 p = {};
                p = __builtin_amdgcn_mfma_f32_16x16x32_bf16(af[mt][0], bfr[nt][0], p, 0, 0, 0);
                p = __builtin_amdgcn_mfma_f32_16x16x32_bf16(af[mt][1], bfr[nt][1], p, 0, 0, 0);
#pragma unroll
                for (int r = 0; r < 4; ++r) {
                    const int row = wid*32 + mt*16 + lq*4 + r;
                    accO[mt][nt][r] += p[r] * dinv[i][row];
                }
            }
    }
    const float inv3 = 1.f / 3.f;
#pragma unroll
    for (int mt = 0; mt < 2; ++mt)
#pragma unroll
        for (int nt = 0; nt < 4; ++nt)
#pragma unroll
            for (int r = 0; r < 4; ++r) {
                const int row = wid*32 + mt*16 + lq*4 + r;
                const int col = nt*16 + l15;
                const float qv = bf2f((unsigned short)qs[(col >> 3)*1024 + row*8 + (col & 7)]);
                Qo[(size_t)(m0 + row) * D_MODEL + h*64 + col] = f2bf((qv + accO[mt][nt][r]) * inv3);
            }
}

extern "C" void kernel_launch(void* const* d_in, const int* in_sizes, int n_in,
                              void* d_out, int out_size, void* d_ws, size_t ws_size,
                              hipStream_t stream)
{
    const float* x      = (const float*)d_in[0];
    const float* emb[3] = {(const float*)d_in[1], (const float*)d_in[2], (const float*)d_in[3]};
    const float* Wq = (const float*)d_in[4];
    const float* bq = (const float*)d_in[5];
    const float* Wk = (const float*)d_in[6];
    const float* bk = (const float*)d_in[7];
    const float* Wv = (const float*)d_in[8];
    const float* bv = (const float*)d_in[9];
    const float* Wo = (const float*)d_in[10];
    const float* bo = (const float*)d_in[11];
    const int* mask[3] = {(const int*)d_in[12], (const int*)d_in[13], (const int*)d_in[14]};
    float* out = (float*)d_out;

    float* ws = (float*)d_ws;
    unsigned short* qb   = (unsigned short*)(ws + Q_OFF);
    unsigned short* kT   = (unsigned short*)(ws + KT_OFF);
    unsigned short* vT   = (unsigned short*)(ws + VT_OFF);
    unsigned short* xb   = (unsigned short*)(ws + XB_OFF);
    unsigned short* q2b  = (unsigned short*)(ws + Q2_OFF);
    unsigned short* embb = (unsigned short*)(ws + EMBB_OFF);
    unsigned short* wb   = (unsigned short*)(ws + WB_OFF);
    unsigned short* wqb  = wb;
    unsigned short* wkb  = wb + 262144;
    unsigned short* wvb  = wb + 1048576;
    unsigned short* wob  = wb + 1835008;
    float* kv   = ws + KV_OFF;
    float* ksum = ws + KS_OFF;
    unsigned short* kvb16 = (unsigned short*)(ws + KVB_OFF);
    int*   flag = (int*)(ws + FLAG_OFF);

    mask_mode_kernel<<<1, 256, 0, stream>>>(mask[0], flag);
    hipMemsetAsync(kv, 0, (size_t)(NUM_I*B_*NH*HD_*HD_ + NUM_I*B_*NH*HD_) * sizeof(float), stream);

    f2bf_kernel<<<8192, 256, 0, stream>>>(x,  xb,  2097152);
    f2bf_kernel<<<128,  256, 0, stream>>>(Wq, wqb, 32768);
    f2bf_kernel<<<384,  256, 0, stream>>>(Wk, wkb, 98304);
    f2bf_kernel<<<384,  256, 0, stream>>>(Wv, wvb, 98304);
    f2bf_kernel<<<128,  256, 0, stream>>>(Wo, wob, 32768);

    const dim3 gq(B_*NSEQ/128, D_MODEL/128);   // (256, 4)
    const dim3 gk(B_*SSEQ/128, D_MODEL/128);   // (128, 4)

    proj_mfma<1, 1><<<gq, 256, 0, stream>>>(xb, wqb, bq, nullptr, nullptr, qb);
    for (int i = 0; i < NUM_I; ++i) {
        f2bf_kernel<<<4096, 256, 0, stream>>>(emb[i], embb, 1048576);
        proj_mfma<2, 2><<<gk, 256, 0, stream>>>(embb, wkb + (size_t)i*262144,
                                                bk + (size_t)i*D_MODEL, mask[i], flag, kT);
        proj_mfma<0, 2><<<gk, 256, 0, stream>>>(embb, wvb + (size_t)i*262144,
                                                bv + (size_t)i*D_MODEL, nullptr, nullptr, vT);
        kv_accum_mfma<<<dim3(8, NH, B_), 256, 0, stream>>>(kT, vT, kv, ksum, i);
    }
    f2bf_kernel<<<192, 256, 0, stream>>>(kv, kvb16, 49152);
    combine_mfma<<<dim3(B_*NSEQ/128, NH), 256, 0, stream>>>(qb, kvb16, ksum, q2b);
    proj_mfma<0, 0><<<gq, 256, 0, stream>>>(q2b, wob, bo, nullptr, nullptr, out);
}